// Round 2
// baseline (661.949 us; speedup 1.0000x reference)
//
#include <hip/hip_runtime.h>
#include <hip/hip_bf16.h>

#define NB 4
#define NC 64
#define NN 6400
#define NSEG 4
#define SEGK (NN / NSEG)          // 1600 keys per segment
#define BN_EPS 1e-5f
#define THR2 11.0f                // defer-max threshold (base-2 logits)

typedef __attribute__((ext_vector_type(4))) float f32x4;
typedef __attribute__((ext_vector_type(8))) __bf16 bf16x8;

static __device__ __forceinline__ f32x4 mfma_bf16(bf16x8 a, bf16x8 b, f32x4 c) {
    return __builtin_amdgcn_mfma_f32_16x16x32_bf16(a, b, c, 0, 0, 0);
}
static __device__ __forceinline__ float fexp2(float x) {
    return __builtin_amdgcn_exp2f(x);
}

// ---------------------------------------------------------------------------
// Kernel 1: theta/phi/g 1x1 convs. theta is pre-scaled by log2(e) so the
// attention softmax can use raw v_exp_f32 (base-2).
//   Qh/Ql  [B][N][C] bf16 hi/lo split of theta*log2e
//   Kh/Kl  [B][N][C] bf16 hi/lo split of phi^T
//   Vt     [B][C][N] bf16 of g
// ---------------------------------------------------------------------------
__global__ __launch_bounds__(256) void k_qkv(
    const float* __restrict__ x,
    const float* __restrict__ w_th, const float* __restrict__ b_th,
    const float* __restrict__ w_ph, const float* __restrict__ b_ph,
    const float* __restrict__ w_g,  const float* __restrict__ b_g,
    __hip_bfloat16* __restrict__ Qh, __hip_bfloat16* __restrict__ Ql,
    __hip_bfloat16* __restrict__ Kh, __hip_bfloat16* __restrict__ Kl,
    __hip_bfloat16* __restrict__ Vt)
{
    __shared__ float xs[NC][68];   // [c][p], padded
    __shared__ float ws[NC][65];   // [c][o], transposed weights, padded

    const int bid = blockIdx.x;
    const int b   = bid / (NN / 64);
    const int n0  = (bid % (NN / 64)) * 64;
    const int t   = threadIdx.x;
    const int o   = t & 63;
    const int pr  = (t >> 6) * 16;

    {   // stage x tile: x[b][c][n0 .. n0+64)
        const int r  = t >> 2;
        const int cc = (t & 3) * 16;
        const float4* src = reinterpret_cast<const float4*>(x + (size_t)(b * NC + r) * NN + n0 + cc);
        float4* dst = reinterpret_cast<float4*>(&xs[r][cc]);
        dst[0] = src[0]; dst[1] = src[1]; dst[2] = src[2]; dst[3] = src[3];
    }

    const float* wptr[3] = { w_th, w_ph, w_g };
    const float* bptr[3] = { b_th, b_ph, b_g };

    #pragma unroll
    for (int cv = 0; cv < 3; ++cv) {
        __syncthreads();
        {
            const int oo = t & 63;
            const int cb = (t >> 6) * 16;
            const float4* src = reinterpret_cast<const float4*>(wptr[cv] + oo * NC + cb);
            float4 a0 = src[0], a1 = src[1], a2 = src[2], a3 = src[3];
            ws[cb +  0][oo] = a0.x; ws[cb +  1][oo] = a0.y; ws[cb +  2][oo] = a0.z; ws[cb +  3][oo] = a0.w;
            ws[cb +  4][oo] = a1.x; ws[cb +  5][oo] = a1.y; ws[cb +  6][oo] = a1.z; ws[cb +  7][oo] = a1.w;
            ws[cb +  8][oo] = a2.x; ws[cb +  9][oo] = a2.y; ws[cb + 10][oo] = a2.z; ws[cb + 11][oo] = a2.w;
            ws[cb + 12][oo] = a3.x; ws[cb + 13][oo] = a3.y; ws[cb + 14][oo] = a3.z; ws[cb + 15][oo] = a3.w;
        }
        __syncthreads();

        float acc[16];
        const float bb = bptr[cv][o];
        #pragma unroll
        for (int i = 0; i < 16; ++i) acc[i] = bb;

        #pragma unroll 8
        for (int c = 0; c < NC; ++c) {
            const float wv = ws[c][o];
            const float4* xr = reinterpret_cast<const float4*>(&xs[c][pr]);
            #pragma unroll
            for (int q = 0; q < 4; ++q) {
                const float4 xv = xr[q];
                acc[4*q + 0] = fmaf(wv, xv.x, acc[4*q + 0]);
                acc[4*q + 1] = fmaf(wv, xv.y, acc[4*q + 1]);
                acc[4*q + 2] = fmaf(wv, xv.z, acc[4*q + 2]);
                acc[4*q + 3] = fmaf(wv, xv.w, acc[4*q + 3]);
            }
        }

        if (cv < 2) {
            __hip_bfloat16* Hh = (cv == 0) ? Qh : Kh;
            __hip_bfloat16* Hl = (cv == 0) ? Ql : Kl;
            const float sc = (cv == 0) ? 1.44269504f : 1.0f;   // fold log2(e) into theta
            #pragma unroll
            for (int pp = 0; pp < 16; ++pp) {
                const float a = acc[pp] * sc;
                const __hip_bfloat16 h  = __float2bfloat16(a);
                const __hip_bfloat16 lo = __float2bfloat16(a - __bfloat162float(h));
                const size_t off = (size_t)(b * NN + n0 + pr + pp) * NC + o;
                Hh[off] = h;
                Hl[off] = lo;
            }
        } else {
            alignas(16) unsigned short gv[16];
            #pragma unroll
            for (int pp = 0; pp < 16; ++pp) {
                const __hip_bfloat16 h = __float2bfloat16(acc[pp]);
                gv[pp] = __builtin_bit_cast(unsigned short, h);
            }
            uint4* dst = reinterpret_cast<uint4*>(Vt + (size_t)(b * NC + o) * NN + n0 + pr);
            const uint4* srcv = reinterpret_cast<const uint4*>(gv);
            dst[0] = srcv[0];
            dst[1] = srcv[1];
        }
    }
}

// ---------------------------------------------------------------------------
// Kernel 2: flash attention with KV-split (NSEG segments per q-tile).
// No __syncthreads in the main loop: K/V fragments loaded straight from
// global (L2-resident; XCD swizzle pins each (b,seg) group to one XCD).
// Defer-max online softmax; per-lane l partials reduced once at the end.
// Writes unnormalized partial O (bf16) + per-row (m, l).
// ---------------------------------------------------------------------------
__global__ __launch_bounds__(256) void k_attn(
    const __hip_bfloat16* __restrict__ Qh, const __hip_bfloat16* __restrict__ Ql,
    const __hip_bfloat16* __restrict__ Kh, const __hip_bfloat16* __restrict__ Kl,
    const __hip_bfloat16* __restrict__ Vt,
    __hip_bfloat16* __restrict__ Op, float* __restrict__ Mm, float* __restrict__ Ll)
{
    __shared__ __hip_bfloat16 Ps[4][16][40];   // per-wave P transpose buffer

    // XCD-aware swizzle: physical bid -> logical so each XCD owns contiguous
    // logical chunk (2 (b,seg) groups -> ~1.2 MB K/V working set per XCD L2).
    const int phys = blockIdx.x;
    const int lid  = (phys & 7) * (NB * NSEG * 100 / 8) + (phys >> 3);
    const int grp  = lid / 100;          // 0..15 = b*NSEG + seg
    const int qt   = lid % 100;
    const int b    = grp >> 2;
    const int seg  = grp & 3;
    const int q0   = qt * 64;

    const int t   = threadIdx.x;
    const int w   = t >> 6;
    const int l   = t & 63;
    const int l16 = l & 15;
    const int lg  = l >> 4;

    // Q fragments (A operand): row = l16, k = lg*8 + j
    const size_t qrow = (size_t)(b * NN + q0 + w * 16 + l16) * NC;
    const bf16x8 qh0 = *reinterpret_cast<const bf16x8*>(Qh + qrow + lg * 8);
    const bf16x8 qh1 = *reinterpret_cast<const bf16x8*>(Qh + qrow + 32 + lg * 8);
    const bf16x8 ql0 = *reinterpret_cast<const bf16x8*>(Ql + qrow + lg * 8);
    const bf16x8 ql1 = *reinterpret_cast<const bf16x8*>(Ql + qrow + 32 + lg * 8);

    f32x4 accO[4];
    float mr[4], rsum[4];
    const f32x4 zero4 = {0.f, 0.f, 0.f, 0.f};
    #pragma unroll
    for (int i = 0; i < 4; ++i) { accO[i] = zero4; mr[i] = -3.0e38f; rsum[i] = 0.f; }

    const __hip_bfloat16* khB = Kh + (size_t)(b * NN + seg * SEGK) * NC;
    const __hip_bfloat16* klB = Kl + (size_t)(b * NN + seg * SEGK) * NC;
    const __hip_bfloat16* vtB = Vt + (size_t)b * NC * NN + seg * SEGK;

    const int koffA = (l16)      * NC + lg * 8;   // subtile 0 rows
    const int koffB = (16 + l16) * NC + lg * 8;   // subtile 1 rows
    const int voff  = l16 * NN + lg * 8;          // V frag base (row c4*16+l16)

    for (int it = 0; it < SEGK / 32; ++it) {
        const __hip_bfloat16* kh0 = khB + it * 32 * NC;
        const __hip_bfloat16* kl0 = klB + it * 32 * NC;

        const bf16x8 kh00 = *reinterpret_cast<const bf16x8*>(kh0 + koffA);
        const bf16x8 kh01 = *reinterpret_cast<const bf16x8*>(kh0 + koffA + 32);
        const bf16x8 kl00 = *reinterpret_cast<const bf16x8*>(kl0 + koffA);
        const bf16x8 kl01 = *reinterpret_cast<const bf16x8*>(kl0 + koffA + 32);
        const bf16x8 kh10 = *reinterpret_cast<const bf16x8*>(kh0 + koffB);
        const bf16x8 kh11 = *reinterpret_cast<const bf16x8*>(kh0 + koffB + 32);
        const bf16x8 kl10 = *reinterpret_cast<const bf16x8*>(kl0 + koffB);
        const bf16x8 kl11 = *reinterpret_cast<const bf16x8*>(kl0 + koffB + 32);

        // ---- QK^T (base-2 logits), hi/lo split ----
        f32x4 s0 = zero4, s1 = zero4;
        s0 = mfma_bf16(qh0, kh00, s0);
        s0 = mfma_bf16(qh1, kh01, s0);
        s0 = mfma_bf16(ql0, kh00, s0);
        s0 = mfma_bf16(ql1, kh01, s0);
        s0 = mfma_bf16(qh0, kl00, s0);
        s0 = mfma_bf16(qh1, kl01, s0);
        s1 = mfma_bf16(qh0, kh10, s1);
        s1 = mfma_bf16(qh1, kh11, s1);
        s1 = mfma_bf16(ql0, kh10, s1);
        s1 = mfma_bf16(ql1, kh11, s1);
        s1 = mfma_bf16(qh0, kl10, s1);
        s1 = mfma_bf16(qh1, kl11, s1);

        // ---- defer-max check (fast path: no cross-lane ops) ----
        float pm[4];
        float dmax = -3.0e38f;
        #pragma unroll
        for (int r = 0; r < 4; ++r) {
            pm[r] = fmaxf(s0[r], s1[r]);
            dmax  = fmaxf(dmax, pm[r] - mr[r]);
        }
        if (__any(dmax > THR2)) {
            float pmr[4];
            #pragma unroll
            for (int r = 0; r < 4; ++r) pmr[r] = pm[r];
            #pragma unroll
            for (int sh = 1; sh < 16; sh <<= 1) {
                #pragma unroll
                for (int r = 0; r < 4; ++r) pmr[r] = fmaxf(pmr[r], __shfl_xor(pmr[r], sh, 64));
            }
            #pragma unroll
            for (int r = 0; r < 4; ++r) {
                const float nm = fmaxf(mr[r], pmr[r]);
                const float al = fexp2(mr[r] - nm);
                mr[r] = nm;
                rsum[r] *= al;
                accO[0][r] *= al;
                accO[1][r] *= al;
                accO[2][r] *= al;
                accO[3][r] *= al;
            }
        }

        // ---- P = 2^(s-m); per-lane l partials; stash P for transpose ----
        #pragma unroll
        for (int r = 0; r < 4; ++r) {
            const float p0 = fexp2(s0[r] - mr[r]);
            const float p1 = fexp2(s1[r] - mr[r]);
            rsum[r] += p0 + p1;
            Ps[w][lg * 4 + r][l16]      = __float2bfloat16(p0);
            Ps[w][lg * 4 + r][16 + l16] = __float2bfloat16(p1);
        }
        // within-wave write->read: compiler inserts lgkmcnt wait, no barrier

        // ---- PV: A = P[q][key] (K=32), B = V from Vt rows (direct global) ----
        const bf16x8 pa = *reinterpret_cast<const bf16x8*>(&Ps[w][l16][lg * 8]);
        const __hip_bfloat16* v0 = vtB + it * 32 + voff;
        #pragma unroll
        for (int c4 = 0; c4 < 4; ++c4) {
            const bf16x8 vb = *reinterpret_cast<const bf16x8*>(v0 + c4 * 16 * NN);
            accO[c4] = mfma_bf16(pa, vb, accO[c4]);
        }
    }

    // ---- final l reduction (once), write partials ----
    float lr[4];
    #pragma unroll
    for (int r = 0; r < 4; ++r) lr[r] = rsum[r];
    #pragma unroll
    for (int sh = 1; sh < 16; sh <<= 1) {
        #pragma unroll
        for (int r = 0; r < 4; ++r) lr[r] += __shfl_xor(lr[r], sh, 64);
    }

    const size_t orow = (size_t)(seg * NB + b) * NN + q0 + w * 16;
    #pragma unroll
    for (int c4 = 0; c4 < 4; ++c4) {
        #pragma unroll
        for (int r = 0; r < 4; ++r) {
            Op[(orow + lg * 4 + r) * NC + c4 * 16 + l16] = __float2bfloat16(accO[c4][r]);
        }
    }
    if (l16 == 0) {
        #pragma unroll
        for (int r = 0; r < 4; ++r) {
            Mm[orow + lg * 4 + r] = mr[r];
            Ll[orow + lg * 4 + r] = lr[r];
        }
    }
}

// ---------------------------------------------------------------------------
// Kernel 3: merge KV-split partials + W conv + BN partial sums
// ---------------------------------------------------------------------------
__global__ __launch_bounds__(256) void k_wconv(
    const __hip_bfloat16* __restrict__ Op, const float* __restrict__ Mm,
    const float* __restrict__ Ll, const float* __restrict__ w_W,
    const float* __restrict__ b_W, float* __restrict__ Wy,
    float* __restrict__ stats)
{
    __shared__ float ys[NC][68];   // [c][p] merged y, transposed
    __shared__ float ws[NC][65];   // [c][o]

    const int bid = blockIdx.x;
    const int b   = bid / (NN / 64);
    const int n0  = (bid % (NN / 64)) * 64;
    const int t   = threadIdx.x;
    const int o   = t & 63;
    const int pr  = (t >> 6) * 16;

    {   // merge 4 segment partials for row n0+p, channels cb..cb+15
        const int p  = t >> 2;
        const int cb = (t & 3) * 16;
        const size_t row = (size_t)b * NN + n0 + p;
        float m[NSEG], lv[NSEG];
        #pragma unroll
        for (int s = 0; s < NSEG; ++s) {
            m[s]  = Mm[(size_t)s * NB * NN + row];
            lv[s] = Ll[(size_t)s * NB * NN + row];
        }
        float mstar = m[0];
        #pragma unroll
        for (int s = 1; s < NSEG; ++s) mstar = fmaxf(mstar, m[s]);
        float acc16[16];
        #pragma unroll
        for (int j = 0; j < 16; ++j) acc16[j] = 0.f;
        float L = 0.f;
        #pragma unroll
        for (int s = 0; s < NSEG; ++s) {
            const float wsc = __builtin_amdgcn_exp2f(m[s] - mstar);
            L += wsc * lv[s];
            const bf16x8 a0 = *reinterpret_cast<const bf16x8*>(Op + ((size_t)s * NB * NN + row) * NC + cb);
            const bf16x8 a1 = *reinterpret_cast<const bf16x8*>(Op + ((size_t)s * NB * NN + row) * NC + cb + 8);
            #pragma unroll
            for (int j = 0; j < 8; ++j) {
                acc16[j]     = fmaf(wsc, (float)a0[j], acc16[j]);
                acc16[8 + j] = fmaf(wsc, (float)a1[j], acc16[8 + j]);
            }
        }
        const float inv = 1.0f / L;
        #pragma unroll
        for (int j = 0; j < 16; ++j) ys[cb + j][p] = acc16[j] * inv;
    }
    {   // stage weights transposed
        const int oo = t & 63;
        const int cb = (t >> 6) * 16;
        const float4* src = reinterpret_cast<const float4*>(w_W + oo * NC + cb);
        float4 a0 = src[0], a1 = src[1], a2 = src[2], a3 = src[3];
        ws[cb +  0][oo] = a0.x; ws[cb +  1][oo] = a0.y; ws[cb +  2][oo] = a0.z; ws[cb +  3][oo] = a0.w;
        ws[cb +  4][oo] = a1.x; ws[cb +  5][oo] = a1.y; ws[cb +  6][oo] = a1.z; ws[cb +  7][oo] = a1.w;
        ws[cb +  8][oo] = a2.x; ws[cb +  9][oo] = a2.y; ws[cb + 10][oo] = a2.z; ws[cb + 11][oo] = a2.w;
        ws[cb + 12][oo] = a3.x; ws[cb + 13][oo] = a3.y; ws[cb + 14][oo] = a3.z; ws[cb + 15][oo] = a3.w;
    }
    __syncthreads();

    float acc[16];
    const float bb = b_W[o];
    #pragma unroll
    for (int i = 0; i < 16; ++i) acc[i] = bb;

    #pragma unroll 8
    for (int c = 0; c < NC; ++c) {
        const float wv = ws[c][o];
        const float4* xr = reinterpret_cast<const float4*>(&ys[c][pr]);
        #pragma unroll
        for (int q = 0; q < 4; ++q) {
            const float4 xv = xr[q];
            acc[4*q + 0] = fmaf(wv, xv.x, acc[4*q + 0]);
            acc[4*q + 1] = fmaf(wv, xv.y, acc[4*q + 1]);
            acc[4*q + 2] = fmaf(wv, xv.z, acc[4*q + 2]);
            acc[4*q + 3] = fmaf(wv, xv.w, acc[4*q + 3]);
        }
    }

    float s1 = 0.f, s2 = 0.f;
    #pragma unroll
    for (int i = 0; i < 16; ++i) { s1 += acc[i]; s2 += acc[i] * acc[i]; }

    float4* dst = reinterpret_cast<float4*>(Wy + (size_t)(b * NC + o) * NN + n0 + pr);
    const float4* av = reinterpret_cast<const float4*>(acc);
    dst[0] = av[0]; dst[1] = av[1]; dst[2] = av[2]; dst[3] = av[3];

    atomicAdd(&stats[o], s1);
    atomicAdd(&stats[NC + o], s2);
}

__global__ void k_zero(float* __restrict__ stats) {
    stats[threadIdx.x] = 0.f;
}

// ---------------------------------------------------------------------------
// Kernel 4: BN (training stats) + gamma/beta + residual
// ---------------------------------------------------------------------------
__global__ __launch_bounds__(256) void k_bn(
    const float* __restrict__ Wy, const float* __restrict__ x,
    const float* __restrict__ stats, const float* __restrict__ gamma,
    const float* __restrict__ beta, float* __restrict__ out)
{
    const int i = blockIdx.x * 256 + threadIdx.x;     // float4 index
    const int c = (i / (NN / 4)) % NC;
    const float n_inv = 1.0f / (float)(NB * NN);
    const float mean = stats[c] * n_inv;
    const float var  = stats[NC + c] * n_inv - mean * mean;
    const float rs   = rsqrtf(var + BN_EPS);
    const float sc   = rs * gamma[c];
    const float sh   = beta[c] - mean * sc;

    const float4 wv = reinterpret_cast<const float4*>(Wy)[i];
    const float4 xv = reinterpret_cast<const float4*>(x)[i];
    float4 ov;
    ov.x = wv.x * sc + sh + xv.x;
    ov.y = wv.y * sc + sh + xv.y;
    ov.z = wv.z * sc + sh + xv.z;
    ov.w = wv.w * sc + sh + xv.w;
    reinterpret_cast<float4*>(out)[i] = ov;
}

// ---------------------------------------------------------------------------
extern "C" void kernel_launch(void* const* d_in, const int* in_sizes, int n_in,
                              void* d_out, int out_size, void* d_ws, size_t ws_size,
                              hipStream_t stream)
{
    const float* x     = (const float*)d_in[0];
    const float* w_th  = (const float*)d_in[1];
    const float* b_th  = (const float*)d_in[2];
    const float* w_ph  = (const float*)d_in[3];
    const float* b_ph  = (const float*)d_in[4];
    const float* w_g   = (const float*)d_in[5];
    const float* b_g   = (const float*)d_in[6];
    const float* w_W   = (const float*)d_in[7];
    const float* b_W   = (const float*)d_in[8];
    const float* gamma = (const float*)d_in[9];
    const float* beta  = (const float*)d_in[10];
    float* out = (float*)d_out;

    char* p = (char*)d_ws;
    const size_t nbh = (size_t)NB * NN * NC * sizeof(__hip_bfloat16);
    __hip_bfloat16* Qh = (__hip_bfloat16*)p; p += nbh;
    __hip_bfloat16* Ql = (__hip_bfloat16*)p; p += nbh;
    __hip_bfloat16* Kh = (__hip_bfloat16*)p; p += nbh;
    __hip_bfloat16* Kl = (__hip_bfloat16*)p; p += nbh;
    __hip_bfloat16* Vt = (__hip_bfloat16*)p; p += nbh;
    __hip_bfloat16* Op = (__hip_bfloat16*)p; p += (size_t)NSEG * NB * NN * NC * sizeof(__hip_bfloat16);
    float* Mm    = (float*)p; p += (size_t)NSEG * NB * NN * sizeof(float);
    float* Ll    = (float*)p; p += (size_t)NSEG * NB * NN * sizeof(float);
    float* stats = (float*)p; p += 2 * NC * sizeof(float);
    // Wy aliases the (dead-by-then) Qh/Ql region
    float* Wy = (float*)d_ws;

    hipLaunchKernelGGL(k_qkv, dim3(NB * NN / 64), dim3(256), 0, stream,
                       x, w_th, b_th, w_ph, b_ph, w_g, b_g, Qh, Ql, Kh, Kl, Vt);
    hipLaunchKernelGGL(k_attn, dim3(NB * NSEG * (NN / 64)), dim3(256), 0, stream,
                       Qh, Ql, Kh, Kl, Vt, Op, Mm, Ll);
    hipLaunchKernelGGL(k_zero, dim3(1), dim3(2 * NC), 0, stream, stats);
    hipLaunchKernelGGL(k_wconv, dim3(NB * NN / 64), dim3(256), 0, stream,
                       Op, Mm, Ll, w_W, b_W, Wy, stats);
    hipLaunchKernelGGL(k_bn, dim3((NB * NC * NN / 4) / 256), dim3(256), 0, stream,
                       Wy, x, stats, gamma, beta, out);
}

// Round 3
// 271.336 us; speedup vs baseline: 2.4396x; 2.4396x over previous
//
#include <hip/hip_runtime.h>
#include <hip/hip_bf16.h>

#define NB 4
#define NC 64
#define NN 6400
#define NSEG 4
#define SEGK (NN / NSEG)          // 1600 keys per segment
#define KVB 32                    // keys per tile
#define NIT (SEGK / KVB)          // 50 iterations
#define QBLK 128                  // q rows per block (4 waves x 32)
#define BN_EPS 1e-5f
#define THR2 11.0f                // defer-max threshold (base-2 logits)

// LDS map (bytes): buf0 @0, buf1 @12288, Ps @24576
//   within buf: KH @0 (4096), KL @4096 (4096), V @8192 (4096)
#define BUFSZ 12288
#define PSOFF 24576
#define LDSSZ (2 * BUFSZ + 4 * 2560)

typedef __attribute__((ext_vector_type(4))) float f32x4;
typedef __attribute__((ext_vector_type(8))) __bf16 bf16x8;

static __device__ __forceinline__ f32x4 mfma_bf16(bf16x8 a, bf16x8 b, f32x4 c) {
    return __builtin_amdgcn_mfma_f32_16x16x32_bf16(a, b, c, 0, 0, 0);
}
static __device__ __forceinline__ float fexp2(float x) { return __builtin_amdgcn_exp2f(x); }
static __device__ __forceinline__ void gld16(const void* g, void* l) {
    __builtin_amdgcn_global_load_lds(
        (const __attribute__((address_space(1))) void*)g,
        (__attribute__((address_space(3))) void*)l, 16, 0, 0);
}
static __device__ __forceinline__ unsigned pk2(float a, float b) {
    unsigned ha = (unsigned)__builtin_bit_cast(unsigned short, __float2bfloat16(a));
    unsigned hb = (unsigned)__builtin_bit_cast(unsigned short, __float2bfloat16(b));
    return ha | (hb << 16);
}

// ---------------------------------------------------------------------------
// Kernel 1: theta/phi/g 1x1 convs. theta pre-scaled by log2(e).
// ---------------------------------------------------------------------------
__global__ __launch_bounds__(256) void k_qkv(
    const float* __restrict__ x,
    const float* __restrict__ w_th, const float* __restrict__ b_th,
    const float* __restrict__ w_ph, const float* __restrict__ b_ph,
    const float* __restrict__ w_g,  const float* __restrict__ b_g,
    __hip_bfloat16* __restrict__ Qh, __hip_bfloat16* __restrict__ Ql,
    __hip_bfloat16* __restrict__ Kh, __hip_bfloat16* __restrict__ Kl,
    __hip_bfloat16* __restrict__ Vt)
{
    __shared__ float xs[NC][68];
    __shared__ float ws[NC][65];

    const int bid = blockIdx.x;
    const int b   = bid / (NN / 64);
    const int n0  = (bid % (NN / 64)) * 64;
    const int t   = threadIdx.x;
    const int o   = t & 63;
    const int pr  = (t >> 6) * 16;

    {
        const int r  = t >> 2;
        const int cc = (t & 3) * 16;
        const float4* src = reinterpret_cast<const float4*>(x + (size_t)(b * NC + r) * NN + n0 + cc);
        float4* dst = reinterpret_cast<float4*>(&xs[r][cc]);
        dst[0] = src[0]; dst[1] = src[1]; dst[2] = src[2]; dst[3] = src[3];
    }

    const float* wptr[3] = { w_th, w_ph, w_g };
    const float* bptr[3] = { b_th, b_ph, b_g };

    #pragma unroll
    for (int cv = 0; cv < 3; ++cv) {
        __syncthreads();
        {
            const int oo = t & 63;
            const int cb = (t >> 6) * 16;
            const float4* src = reinterpret_cast<const float4*>(wptr[cv] + oo * NC + cb);
            float4 a0 = src[0], a1 = src[1], a2 = src[2], a3 = src[3];
            ws[cb +  0][oo] = a0.x; ws[cb +  1][oo] = a0.y; ws[cb +  2][oo] = a0.z; ws[cb +  3][oo] = a0.w;
            ws[cb +  4][oo] = a1.x; ws[cb +  5][oo] = a1.y; ws[cb +  6][oo] = a1.z; ws[cb +  7][oo] = a1.w;
            ws[cb +  8][oo] = a2.x; ws[cb +  9][oo] = a2.y; ws[cb + 10][oo] = a2.z; ws[cb + 11][oo] = a2.w;
            ws[cb + 12][oo] = a3.x; ws[cb + 13][oo] = a3.y; ws[cb + 14][oo] = a3.z; ws[cb + 15][oo] = a3.w;
        }
        __syncthreads();

        float acc[16];
        const float bb = bptr[cv][o];
        #pragma unroll
        for (int i = 0; i < 16; ++i) acc[i] = bb;

        #pragma unroll 8
        for (int c = 0; c < NC; ++c) {
            const float wv = ws[c][o];
            const float4* xr = reinterpret_cast<const float4*>(&xs[c][pr]);
            #pragma unroll
            for (int q = 0; q < 4; ++q) {
                const float4 xv = xr[q];
                acc[4*q + 0] = fmaf(wv, xv.x, acc[4*q + 0]);
                acc[4*q + 1] = fmaf(wv, xv.y, acc[4*q + 1]);
                acc[4*q + 2] = fmaf(wv, xv.z, acc[4*q + 2]);
                acc[4*q + 3] = fmaf(wv, xv.w, acc[4*q + 3]);
            }
        }

        if (cv < 2) {
            __hip_bfloat16* Hh = (cv == 0) ? Qh : Kh;
            __hip_bfloat16* Hl = (cv == 0) ? Ql : Kl;
            const float sc = (cv == 0) ? 1.44269504f : 1.0f;
            #pragma unroll
            for (int pp = 0; pp < 16; ++pp) {
                const float a = acc[pp] * sc;
                const __hip_bfloat16 h  = __float2bfloat16(a);
                const __hip_bfloat16 lo = __float2bfloat16(a - __bfloat162float(h));
                const size_t off = (size_t)(b * NN + n0 + pr + pp) * NC + o;
                Hh[off] = h;
                Hl[off] = lo;
            }
        } else {
            alignas(16) unsigned short gv[16];
            #pragma unroll
            for (int pp = 0; pp < 16; ++pp) {
                const __hip_bfloat16 h = __float2bfloat16(acc[pp]);
                gv[pp] = __builtin_bit_cast(unsigned short, h);
            }
            uint4* dst = reinterpret_cast<uint4*>(Vt + (size_t)(b * NC + o) * NN + n0 + pr);
            const uint4* srcv = reinterpret_cast<const uint4*>(gv);
            dst[0] = srcv[0];
            dst[1] = srcv[1];
        }
    }
}

// ---------------------------------------------------------------------------
// Kernel 2: flash attention, double-buffered global_load_lds staging,
// swapped QK^T (A=K, B=Q), defer-max, end-only l reduction.
// ---------------------------------------------------------------------------
__global__ __launch_bounds__(256, 3) void k_attn(
    const __hip_bfloat16* __restrict__ Qh, const __hip_bfloat16* __restrict__ Ql,
    const __hip_bfloat16* __restrict__ Kh, const __hip_bfloat16* __restrict__ Kl,
    const __hip_bfloat16* __restrict__ Vt,
    __hip_bfloat16* __restrict__ Op, float* __restrict__ Mm, float* __restrict__ Ll)
{
    __shared__ alignas(16) char lds[LDSSZ];

    // bijective XCD swizzle (800 % 8 == 0)
    const int phys = blockIdx.x;
    const int lid  = (phys & 7) * (NB * NSEG * (NN / QBLK) / 8) + (phys >> 3);
    const int grp  = lid / (NN / QBLK);
    const int qt   = lid % (NN / QBLK);
    const int b    = grp >> 2;
    const int seg  = grp & 3;
    const int q0   = qt * QBLK;

    const int t   = threadIdx.x;
    const int w   = t >> 6;
    const int l   = t & 63;
    const int l16 = l & 15;
    const int lg  = l >> 4;

    // Q fragments (B operand): lane (l16,lg) holds Q[q=qs*16+l16][c=lg*8..+7]
    bf16x8 qh[2][2], ql[2][2];
    {
        const size_t qbase = (size_t)(b * NN + q0 + w * 32) * NC;
        #pragma unroll
        for (int qs = 0; qs < 2; ++qs) {
            const size_t ro = qbase + (size_t)(qs * 16 + l16) * NC + lg * 8;
            qh[qs][0] = *reinterpret_cast<const bf16x8*>(Qh + ro);
            qh[qs][1] = *reinterpret_cast<const bf16x8*>(Qh + ro + 32);
            ql[qs][0] = *reinterpret_cast<const bf16x8*>(Ql + ro);
            ql[qs][1] = *reinterpret_cast<const bf16x8*>(Ql + ro + 32);
        }
    }

    const __hip_bfloat16* khB = Kh + (size_t)(b * NN + seg * SEGK) * NC;
    const __hip_bfloat16* klB = Kl + (size_t)(b * NN + seg * SEGK) * NC;
    const __hip_bfloat16* vtB = Vt + (size_t)b * NC * NN + seg * SEGK;

    // staging: lane's LDS slot = w*1024 + lane*16 (linear); global src
    // pre-swizzled so swizzled ds_reads see the right data (rule #21).
    const int goffK = (w * 8 + (l >> 3)) * NC + (((l & 7) ^ (l >> 3)) * 8);
    const int goffV = (w * 16 + (l >> 2)) * NN + (((l & 3) ^ ((l >> 2) & 3)) * 8);

    // swizzled ds_read offsets
    const int swzK = l16 & 7;
    const int kA0  = l16 * 128 + ((lg ^ swzK) * 16);          // keys 0-15, ch chunk lg
    const int kA1  = l16 * 128 + (((lg + 4) ^ swzK) * 16);    // keys 0-15, ch chunk lg+4
    const int swzV = ((lg ^ (l16 & 3)) * 16);
    const int pW   = PSOFF + w * 2560 + l16 * 80 + lg * 8;    // P write (b64)
    const int pR   = PSOFF + w * 2560 + l16 * 80 + lg * 16;   // P read  (b128)

    f32x4 accO[2][4];
    float mr[2], rsum[2];
    const f32x4 zero4 = {0.f, 0.f, 0.f, 0.f};
    #pragma unroll
    for (int qs = 0; qs < 2; ++qs) {
        mr[qs] = -3.0e38f; rsum[qs] = 0.f;
        #pragma unroll
        for (int c4 = 0; c4 < 4; ++c4) accO[qs][c4] = zero4;
    }

    auto STAGE = [&](int key0, char* bK) {
        gld16(khB + (size_t)key0 * NC + goffK, bK + w * 1024);
        gld16(klB + (size_t)key0 * NC + goffK, bK + 4096 + w * 1024);
        gld16(vtB + key0 + goffV,              bK + 8192 + w * 1024);
    };

    STAGE(0, lds);
    __syncthreads();
    int cur = 0;

    for (int it = 0; it < NIT; ++it) {
        char* bK = lds + cur * BUFSZ;
        if (it + 1 < NIT) STAGE((it + 1) * KVB, lds + (cur ^ 1) * BUFSZ);

        // K fragments (A operand), swizzled reads
        const bf16x8 kh0A = *reinterpret_cast<const bf16x8*>(bK + kA0);
        const bf16x8 kh1A = *reinterpret_cast<const bf16x8*>(bK + kA1);
        const bf16x8 kh0B = *reinterpret_cast<const bf16x8*>(bK + 2048 + kA0);
        const bf16x8 kh1B = *reinterpret_cast<const bf16x8*>(bK + 2048 + kA1);
        const bf16x8 kl0A = *reinterpret_cast<const bf16x8*>(bK + 4096 + kA0);
        const bf16x8 kl1A = *reinterpret_cast<const bf16x8*>(bK + 4096 + kA1);
        const bf16x8 kl0B = *reinterpret_cast<const bf16x8*>(bK + 4096 + 2048 + kA0);
        const bf16x8 kl1B = *reinterpret_cast<const bf16x8*>(bK + 4096 + 2048 + kA1);

        // QK^T: D[key][q], hi/lo split, base-2 logits
        f32x4 sA[2], sB[2];
        #pragma unroll
        for (int qs = 0; qs < 2; ++qs) {
            f32x4 s = zero4;
            s = mfma_bf16(kh0A, qh[qs][0], s);
            s = mfma_bf16(kh1A, qh[qs][1], s);
            s = mfma_bf16(kl0A, qh[qs][0], s);
            s = mfma_bf16(kl1A, qh[qs][1], s);
            s = mfma_bf16(kh0A, ql[qs][0], s);
            s = mfma_bf16(kh1A, ql[qs][1], s);
            sA[qs] = s;
            f32x4 u = zero4;
            u = mfma_bf16(kh0B, qh[qs][0], u);
            u = mfma_bf16(kh1B, qh[qs][1], u);
            u = mfma_bf16(kl0B, qh[qs][0], u);
            u = mfma_bf16(kl1B, qh[qs][1], u);
            u = mfma_bf16(kh0B, ql[qs][0], u);
            u = mfma_bf16(kh1B, ql[qs][1], u);
            sB[qs] = u;
        }

        // defer-max online softmax (lane owns 8 keys of q = qs*16 + l16)
        float pm[2];
        #pragma unroll
        for (int qs = 0; qs < 2; ++qs) {
            pm[qs] = fmaxf(fmaxf(fmaxf(sA[qs][0], sA[qs][1]), fmaxf(sA[qs][2], sA[qs][3])),
                           fmaxf(fmaxf(sB[qs][0], sB[qs][1]), fmaxf(sB[qs][2], sB[qs][3])));
        }
        const float dmax = fmaxf(pm[0] - mr[0], pm[1] - mr[1]);
        if (__any(dmax > THR2)) {
            float m0 = pm[0], m1 = pm[1];
            m0 = fmaxf(m0, __shfl_xor(m0, 16, 64));
            m0 = fmaxf(m0, __shfl_xor(m0, 32, 64));
            m1 = fmaxf(m1, __shfl_xor(m1, 16, 64));
            m1 = fmaxf(m1, __shfl_xor(m1, 32, 64));
            const float n0 = fmaxf(mr[0], m0), n1 = fmaxf(mr[1], m1);
            const float a0 = fexp2(mr[0] - n0), a1 = fexp2(mr[1] - n1);
            mr[0] = n0; mr[1] = n1;
            rsum[0] *= a0; rsum[1] *= a1;
            // accO rows are q_local = lg*4+r -> fetch alpha from lane lg*4+r
            #pragma unroll
            for (int r = 0; r < 4; ++r) {
                const float b0 = __shfl(a0, lg * 4 + r, 64);
                const float b1 = __shfl(a1, lg * 4 + r, 64);
                #pragma unroll
                for (int c4 = 0; c4 < 4; ++c4) {
                    accO[0][c4][r] *= b0;
                    accO[1][c4][r] *= b1;
                }
            }
        }

        // P = 2^(s-m), pack 4 consecutive keys -> one ds_write_b64
        #pragma unroll
        for (int qs = 0; qs < 2; ++qs) {
            float pA[4], pB[4];
            #pragma unroll
            for (int r = 0; r < 4; ++r) {
                pA[r] = fexp2(sA[qs][r] - mr[qs]);
                pB[r] = fexp2(sB[qs][r] - mr[qs]);
            }
            rsum[qs] += (pA[0] + pA[1] + pA[2] + pA[3]) + (pB[0] + pB[1] + pB[2] + pB[3]);
            *reinterpret_cast<uint2*>(lds + pW + qs * 1280)      = make_uint2(pk2(pA[0], pA[1]), pk2(pA[2], pA[3]));
            *reinterpret_cast<uint2*>(lds + pW + qs * 1280 + 32) = make_uint2(pk2(pB[0], pB[1]), pk2(pB[2], pB[3]));
        }

        // PV: A = P[q][key], B = V[key][ch] (within-wave P round trip)
        #pragma unroll
        for (int qs = 0; qs < 2; ++qs) {
            const bf16x8 pa = *reinterpret_cast<const bf16x8*>(lds + pR + qs * 1280);
            #pragma unroll
            for (int c4 = 0; c4 < 4; ++c4) {
                const bf16x8 vb = *reinterpret_cast<const bf16x8*>(bK + 8192 + (c4 * 16 + l16) * 64 + swzV);
                accO[qs][c4] = mfma_bf16(pa, vb, accO[qs][c4]);
            }
        }

        __syncthreads();
        cur ^= 1;
    }

    // final l reduction over the 4 lanes sharing each q
    float rs[2] = { rsum[0], rsum[1] };
    #pragma unroll
    for (int qs = 0; qs < 2; ++qs) {
        rs[qs] += __shfl_xor(rs[qs], 16, 64);
        rs[qs] += __shfl_xor(rs[qs], 32, 64);
    }

    const size_t orow = (size_t)(seg * NB + b) * NN + q0 + w * 32;
    #pragma unroll
    for (int qs = 0; qs < 2; ++qs) {
        #pragma unroll
        for (int c4 = 0; c4 < 4; ++c4) {
            #pragma unroll
            for (int r = 0; r < 4; ++r) {
                Op[(orow + qs * 16 + lg * 4 + r) * NC + c4 * 16 + l16] = __float2bfloat16(accO[qs][c4][r]);
            }
        }
    }
    if (lg == 0) {
        #pragma unroll
        for (int qs = 0; qs < 2; ++qs) {
            Mm[orow + qs * 16 + l16] = mr[qs];
            Ll[orow + qs * 16 + l16] = rs[qs];
        }
    }
}

// ---------------------------------------------------------------------------
// Kernel 3: merge KV-split partials + W conv + BN partial sums
// ---------------------------------------------------------------------------
__global__ __launch_bounds__(256) void k_wconv(
    const __hip_bfloat16* __restrict__ Op, const float* __restrict__ Mm,
    const float* __restrict__ Ll, const float* __restrict__ w_W,
    const float* __restrict__ b_W, float* __restrict__ Wy,
    float* __restrict__ stats)
{
    __shared__ float ys[NC][68];
    __shared__ float ws[NC][65];

    const int bid = blockIdx.x;
    const int b   = bid / (NN / 64);
    const int n0  = (bid % (NN / 64)) * 64;
    const int t   = threadIdx.x;
    const int o   = t & 63;
    const int pr  = (t >> 6) * 16;

    {
        const int p  = t >> 2;
        const int cb = (t & 3) * 16;
        const size_t row = (size_t)b * NN + n0 + p;
        float m[NSEG], lv[NSEG];
        #pragma unroll
        for (int s = 0; s < NSEG; ++s) {
            m[s]  = Mm[(size_t)s * NB * NN + row];
            lv[s] = Ll[(size_t)s * NB * NN + row];
        }
        float mstar = m[0];
        #pragma unroll
        for (int s = 1; s < NSEG; ++s) mstar = fmaxf(mstar, m[s]);
        float acc16[16];
        #pragma unroll
        for (int j = 0; j < 16; ++j) acc16[j] = 0.f;
        float L = 0.f;
        #pragma unroll
        for (int s = 0; s < NSEG; ++s) {
            const float wsc = __builtin_amdgcn_exp2f(m[s] - mstar);
            L += wsc * lv[s];
            const bf16x8 a0 = *reinterpret_cast<const bf16x8*>(Op + ((size_t)s * NB * NN + row) * NC + cb);
            const bf16x8 a1 = *reinterpret_cast<const bf16x8*>(Op + ((size_t)s * NB * NN + row) * NC + cb + 8);
            #pragma unroll
            for (int j = 0; j < 8; ++j) {
                acc16[j]     = fmaf(wsc, (float)a0[j], acc16[j]);
                acc16[8 + j] = fmaf(wsc, (float)a1[j], acc16[8 + j]);
            }
        }
        const float inv = 1.0f / L;
        #pragma unroll
        for (int j = 0; j < 16; ++j) ys[cb + j][p] = acc16[j] * inv;
    }
    {
        const int oo = t & 63;
        const int cb = (t >> 6) * 16;
        const float4* src = reinterpret_cast<const float4*>(w_W + oo * NC + cb);
        float4 a0 = src[0], a1 = src[1], a2 = src[2], a3 = src[3];
        ws[cb +  0][oo] = a0.x; ws[cb +  1][oo] = a0.y; ws[cb +  2][oo] = a0.z; ws[cb +  3][oo] = a0.w;
        ws[cb +  4][oo] = a1.x; ws[cb +  5][oo] = a1.y; ws[cb +  6][oo] = a1.z; ws[cb +  7][oo] = a1.w;
        ws[cb +  8][oo] = a2.x; ws[cb +  9][oo] = a2.y; ws[cb + 10][oo] = a2.z; ws[cb + 11][oo] = a2.w;
        ws[cb + 12][oo] = a3.x; ws[cb + 13][oo] = a3.y; ws[cb + 14][oo] = a3.z; ws[cb + 15][oo] = a3.w;
    }
    __syncthreads();

    float acc[16];
    const float bb = b_W[o];
    #pragma unroll
    for (int i = 0; i < 16; ++i) acc[i] = bb;

    #pragma unroll 8
    for (int c = 0; c < NC; ++c) {
        const float wv = ws[c][o];
        const float4* xr = reinterpret_cast<const float4*>(&ys[c][pr]);
        #pragma unroll
        for (int q = 0; q < 4; ++q) {
            const float4 xv = xr[q];
            acc[4*q + 0] = fmaf(wv, xv.x, acc[4*q + 0]);
            acc[4*q + 1] = fmaf(wv, xv.y, acc[4*q + 1]);
            acc[4*q + 2] = fmaf(wv, xv.z, acc[4*q + 2]);
            acc[4*q + 3] = fmaf(wv, xv.w, acc[4*q + 3]);
        }
    }

    float s1 = 0.f, s2 = 0.f;
    #pragma unroll
    for (int i = 0; i < 16; ++i) { s1 += acc[i]; s2 += acc[i] * acc[i]; }

    float4* dst = reinterpret_cast<float4*>(Wy + (size_t)(b * NC + o) * NN + n0 + pr);
    const float4* av = reinterpret_cast<const float4*>(acc);
    dst[0] = av[0]; dst[1] = av[1]; dst[2] = av[2]; dst[3] = av[3];

    atomicAdd(&stats[o], s1);
    atomicAdd(&stats[NC + o], s2);
}

__global__ void k_zero(float* __restrict__ stats) {
    stats[threadIdx.x] = 0.f;
}

// ---------------------------------------------------------------------------
// Kernel 4: BN (training stats) + gamma/beta + residual
// ---------------------------------------------------------------------------
__global__ __launch_bounds__(256) void k_bn(
    const float* __restrict__ Wy, const float* __restrict__ x,
    const float* __restrict__ stats, const float* __restrict__ gamma,
    const float* __restrict__ beta, float* __restrict__ out)
{
    const int i = blockIdx.x * 256 + threadIdx.x;
    const int c = (i / (NN / 4)) % NC;
    const float n_inv = 1.0f / (float)(NB * NN);
    const float mean = stats[c] * n_inv;
    const float var  = stats[NC + c] * n_inv - mean * mean;
    const float rsq  = rsqrtf(var + BN_EPS);
    const float sc   = rsq * gamma[c];
    const float sh   = beta[c] - mean * sc;

    const float4 wv = reinterpret_cast<const float4*>(Wy)[i];
    const float4 xv = reinterpret_cast<const float4*>(x)[i];
    float4 ov;
    ov.x = wv.x * sc + sh + xv.x;
    ov.y = wv.y * sc + sh + xv.y;
    ov.z = wv.z * sc + sh + xv.z;
    ov.w = wv.w * sc + sh + xv.w;
    reinterpret_cast<float4*>(out)[i] = ov;
}

// ---------------------------------------------------------------------------
extern "C" void kernel_launch(void* const* d_in, const int* in_sizes, int n_in,
                              void* d_out, int out_size, void* d_ws, size_t ws_size,
                              hipStream_t stream)
{
    const float* x     = (const float*)d_in[0];
    const float* w_th  = (const float*)d_in[1];
    const float* b_th  = (const float*)d_in[2];
    const float* w_ph  = (const float*)d_in[3];
    const float* b_ph  = (const float*)d_in[4];
    const float* w_g   = (const float*)d_in[5];
    const float* b_g   = (const float*)d_in[6];
    const float* w_W   = (const float*)d_in[7];
    const float* b_W   = (const float*)d_in[8];
    const float* gamma = (const float*)d_in[9];
    const float* beta  = (const float*)d_in[10];
    float* out = (float*)d_out;

    char* p = (char*)d_ws;
    const size_t nbh = (size_t)NB * NN * NC * sizeof(__hip_bfloat16);
    __hip_bfloat16* Qh = (__hip_bfloat16*)p; p += nbh;
    __hip_bfloat16* Ql = (__hip_bfloat16*)p; p += nbh;
    __hip_bfloat16* Kh = (__hip_bfloat16*)p; p += nbh;
    __hip_bfloat16* Kl = (__hip_bfloat16*)p; p += nbh;
    __hip_bfloat16* Vt = (__hip_bfloat16*)p; p += nbh;
    __hip_bfloat16* Op = (__hip_bfloat16*)p; p += (size_t)NSEG * NB * NN * NC * sizeof(__hip_bfloat16);
    float* Mm    = (float*)p; p += (size_t)NSEG * NB * NN * sizeof(float);
    float* Ll    = (float*)p; p += (size_t)NSEG * NB * NN * sizeof(float);
    float* stats = (float*)p; p += 2 * NC * sizeof(float);
    float* Wy = (float*)d_ws;   // aliases dead-by-then Qh/Ql region

    hipLaunchKernelGGL(k_qkv, dim3(NB * NN / 64), dim3(256), 0, stream,
                       x, w_th, b_th, w_ph, b_ph, w_g, b_g, Qh, Ql, Kh, Kl, Vt);
    hipLaunchKernelGGL(k_attn, dim3(NB * NSEG * (NN / QBLK)), dim3(256), 0, stream,
                       Qh, Ql, Kh, Kl, Vt, Op, Mm, Ll);
    hipLaunchKernelGGL(k_zero, dim3(1), dim3(2 * NC), 0, stream, stats);
    hipLaunchKernelGGL(k_wconv, dim3(NB * NN / 64), dim3(256), 0, stream,
                       Op, Mm, Ll, w_W, b_W, Wy, stats);
    hipLaunchKernelGGL(k_bn, dim3((NB * NC * NN / 4) / 256), dim3(256), 0, stream,
                       Wy, x, stats, gamma, beta, out);
}

// Round 7
// 236.415 us; speedup vs baseline: 2.8000x; 1.1477x over previous
//
#include <hip/hip_runtime.h>
#include <hip/hip_bf16.h>

#define NB 4
#define NC 64
#define NN 6400
#define KVB 32                    // keys per tile
#define QBLK 128                  // q rows per block (4 waves x 32)
#define BN_EPS 1e-5f
#define THR2 11.0f                // defer-max threshold (base-2 logits)

// k_attn LDS map (bytes): 2 double-buffered staging bufs only (no P buffer)
//   within buf: KH @0 (4096), KL @4096 (4096), V @8192 (4096)
#define BUFSZ 12288

typedef __attribute__((ext_vector_type(4))) float  f32x4;
typedef __attribute__((ext_vector_type(8))) __bf16 bf16x8;

static __device__ __forceinline__ f32x4 mfma_bf16(bf16x8 a, bf16x8 b, f32x4 c) {
    return __builtin_amdgcn_mfma_f32_16x16x32_bf16(a, b, c, 0, 0, 0);
}
static __device__ __forceinline__ float fexp2(float x) { return __builtin_amdgcn_exp2f(x); }
static __device__ __forceinline__ void gld16(const void* g, void* l) {
    __builtin_amdgcn_global_load_lds(
        (const __attribute__((address_space(1))) void*)g,
        (__attribute__((address_space(3))) void*)l, 16, 0, 0);
}
// pack two f32 -> 2x bf16 in a u32 (low = a, high = b); proven in r1-r3
static __device__ __forceinline__ unsigned pk2(float a, float b) {
    unsigned ha = (unsigned)__builtin_bit_cast(unsigned short, __float2bfloat16(a));
    unsigned hb = (unsigned)__builtin_bit_cast(unsigned short, __float2bfloat16(b));
    return ha | (hb << 16);
}

// ---------------------------------------------------------------------------
// Kernel 1: theta/phi/g 1x1 convs, 32-position tiles (grid 800).
//   Qh/Ql [B][N][C] bf16 hi/lo of theta*log2e ; Kh/Kl same for phi ; Vt [B][C][N]
// ---------------------------------------------------------------------------
__global__ __launch_bounds__(256) void k_qkv(
    const float* __restrict__ x,
    const float* __restrict__ w_th, const float* __restrict__ b_th,
    const float* __restrict__ w_ph, const float* __restrict__ b_ph,
    const float* __restrict__ w_g,  const float* __restrict__ b_g,
    __hip_bfloat16* __restrict__ Qh, __hip_bfloat16* __restrict__ Ql,
    __hip_bfloat16* __restrict__ Kh, __hip_bfloat16* __restrict__ Kl,
    __hip_bfloat16* __restrict__ Vt)
{
    __shared__ float xs[NC][36];   // [c][p], 32 pos + pad
    __shared__ float ws[NC][65];   // [c][o], transposed weights

    const int bid = blockIdx.x;
    const int b   = bid / (NN / 32);
    const int n0  = (bid % (NN / 32)) * 32;
    const int t   = threadIdx.x;
    const int o   = t & 63;
    const int pr  = (t >> 6) * 8;

    {   // stage x tile: x[b][c][n0..n0+32)
        const int r  = t >> 2;
        const int cc = (t & 3) * 8;
        const float4* src = reinterpret_cast<const float4*>(x + (size_t)(b * NC + r) * NN + n0 + cc);
        float4* dst = reinterpret_cast<float4*>(&xs[r][cc]);
        dst[0] = src[0]; dst[1] = src[1];
    }

    const float* wptr[3] = { w_th, w_ph, w_g };
    const float* bptr[3] = { b_th, b_ph, b_g };

    #pragma unroll
    for (int cv = 0; cv < 3; ++cv) {
        __syncthreads();
        {
            const int oo = t & 63;
            const int cb = (t >> 6) * 16;
            const float4* src = reinterpret_cast<const float4*>(wptr[cv] + oo * NC + cb);
            float4 a0 = src[0], a1 = src[1], a2 = src[2], a3 = src[3];
            ws[cb +  0][oo] = a0.x; ws[cb +  1][oo] = a0.y; ws[cb +  2][oo] = a0.z; ws[cb +  3][oo] = a0.w;
            ws[cb +  4][oo] = a1.x; ws[cb +  5][oo] = a1.y; ws[cb +  6][oo] = a1.z; ws[cb +  7][oo] = a1.w;
            ws[cb +  8][oo] = a2.x; ws[cb +  9][oo] = a2.y; ws[cb + 10][oo] = a2.z; ws[cb + 11][oo] = a2.w;
            ws[cb + 12][oo] = a3.x; ws[cb + 13][oo] = a3.y; ws[cb + 14][oo] = a3.z; ws[cb + 15][oo] = a3.w;
        }
        __syncthreads();

        float acc[8];
        const float bb = bptr[cv][o];
        #pragma unroll
        for (int i = 0; i < 8; ++i) acc[i] = bb;

        #pragma unroll 8
        for (int c = 0; c < NC; ++c) {
            const float wv = ws[c][o];
            const float4* xr = reinterpret_cast<const float4*>(&xs[c][pr]);
            #pragma unroll
            for (int q = 0; q < 2; ++q) {
                const float4 xv = xr[q];
                acc[4*q + 0] = fmaf(wv, xv.x, acc[4*q + 0]);
                acc[4*q + 1] = fmaf(wv, xv.y, acc[4*q + 1]);
                acc[4*q + 2] = fmaf(wv, xv.z, acc[4*q + 2]);
                acc[4*q + 3] = fmaf(wv, xv.w, acc[4*q + 3]);
            }
        }

        if (cv < 2) {
            __hip_bfloat16* Hh = (cv == 0) ? Qh : Kh;
            __hip_bfloat16* Hl = (cv == 0) ? Ql : Kl;
            const float sc = (cv == 0) ? 1.44269504f : 1.0f;   // fold log2(e) into theta
            #pragma unroll
            for (int pp = 0; pp < 8; ++pp) {
                const float a = acc[pp] * sc;
                const __hip_bfloat16 h  = __float2bfloat16(a);
                const __hip_bfloat16 lo = __float2bfloat16(a - __bfloat162float(h));
                const size_t off = (size_t)(b * NN + n0 + pr + pp) * NC + o;
                Hh[off] = h;
                Hl[off] = lo;
            }
        } else {
            alignas(16) unsigned short gv[8];
            #pragma unroll
            for (int pp = 0; pp < 8; ++pp)
                gv[pp] = __builtin_bit_cast(unsigned short, __float2bfloat16(acc[pp]));
            *reinterpret_cast<uint4*>(Vt + (size_t)(b * NC + o) * NN + n0 + pr) =
                *reinterpret_cast<const uint4*>(gv);
        }
    }
}

// ---------------------------------------------------------------------------
// Kernel 2: flash attention, KV-split NS segments, double-buffered
// global_load_lds staging, swapped QK^T (A=K, B=Q), in-register P fed to a
// concat-K=32 PV (proven 16x16x32 intrinsic; key->kslot bijection applied
// identically to A and B sides), defer-max softmax.
// ---------------------------------------------------------------------------
template<int NS>
__global__ __launch_bounds__(256, 4) void k_attn(
    const __hip_bfloat16* __restrict__ Qh, const __hip_bfloat16* __restrict__ Ql,
    const __hip_bfloat16* __restrict__ Kh, const __hip_bfloat16* __restrict__ Kl,
    const __hip_bfloat16* __restrict__ Vt,
    __hip_bfloat16* __restrict__ Op, float* __restrict__ Mm, float* __restrict__ Ll)
{
    constexpr int SEGK = NN / NS;
    constexpr int NIT  = SEGK / KVB;
    constexpr int NQT  = NN / QBLK;
    constexpr int CPX  = NB * NS * NQT / 8;

    __shared__ alignas(16) char lds[2 * BUFSZ];

    // bijective XCD swizzle (grid % 8 == 0)
    const int phys = blockIdx.x;
    const int lid  = (phys & 7) * CPX + (phys >> 3);
    const int grp  = lid / NQT;
    const int qt   = lid % NQT;
    const int b    = grp / NS;
    const int seg  = grp % NS;
    const int q0   = qt * QBLK;

    const int t   = threadIdx.x;
    const int w   = t >> 6;
    const int l   = t & 63;
    const int l16 = l & 15;
    const int lg  = l >> 4;

    // Q fragments (B operand of QK): lane holds Q[q=qs*16+l16][c=lg*8..+7]
    bf16x8 qh[2][2], ql[2][2];
    {
        const size_t qbase = (size_t)(b * NN + q0 + w * 32) * NC;
        #pragma unroll
        for (int qs = 0; qs < 2; ++qs) {
            const size_t ro = qbase + (size_t)(qs * 16 + l16) * NC + lg * 8;
            qh[qs][0] = *reinterpret_cast<const bf16x8*>(Qh + ro);
            qh[qs][1] = *reinterpret_cast<const bf16x8*>(Qh + ro + 32);
            ql[qs][0] = *reinterpret_cast<const bf16x8*>(Ql + ro);
            ql[qs][1] = *reinterpret_cast<const bf16x8*>(Ql + ro + 32);
        }
    }

    const __hip_bfloat16* khB = Kh + (size_t)(b * NN + seg * SEGK) * NC;
    const __hip_bfloat16* klB = Kl + (size_t)(b * NN + seg * SEGK) * NC;
    const __hip_bfloat16* vtB = Vt + (size_t)b * NC * NN + seg * SEGK;

    // staging: LDS dest linear (base + lane*16); global src pre-swizzled
    const int goffK = (w * 8 + (l >> 3)) * NC + (((l & 7) ^ (l >> 3)) * 8);
    const int goffV = (w * 16 + (l >> 2)) * NN + (((l & 3) ^ ((l >> 2) & 3)) * 8);

    // swizzled K ds_read offsets (b128): chunk c of key k at k*128 + (c^(k&7))*16
    const int swzK = l16 & 7;
    const int kA0  = l16 * 128 + ((lg ^ swzK) * 16);
    const int kA1  = l16 * 128 + (((lg + 4) ^ swzK) * 16);
    // V b64 read offsets: chunk c of channel r at r*64 + (c^(r&3))*16
    //   vA: keys lg*4..+3  -> chunk lg>>1,     within-chunk byte (lg&1)*8
    //   vB: keys 16+lg*4.. -> chunk 2+(lg>>1), within-chunk byte (lg&1)*8
    const int slotA = (((lg >> 1) ^ (l16 & 3)) * 16) + (lg & 1) * 8;
    const int slotB = (((2 + (lg >> 1)) ^ (l16 & 3)) * 16) + (lg & 1) * 8;

    f32x4 accO[2][4];
    float mr[2], rsum[2];
    const f32x4 zero4 = {0.f, 0.f, 0.f, 0.f};
    #pragma unroll
    for (int qs = 0; qs < 2; ++qs) {
        mr[qs] = -3.0e38f; rsum[qs] = 0.f;
        #pragma unroll
        for (int c4 = 0; c4 < 4; ++c4) accO[qs][c4] = zero4;
    }

    auto STAGE = [&](int key0, char* bK) {
        gld16(khB + (size_t)key0 * NC + goffK, bK + w * 1024);
        gld16(klB + (size_t)key0 * NC + goffK, bK + 4096 + w * 1024);
        gld16(vtB + key0 + goffV,              bK + 8192 + w * 1024);
    };

    STAGE(0, lds);
    __syncthreads();
    int cur = 0;

    for (int it = 0; it < NIT; ++it) {
        char* bK = lds + cur * BUFSZ;
        if (it + 1 < NIT) STAGE((it + 1) * KVB, lds + (cur ^ 1) * BUFSZ);

        // ---- K fragments (A operand), swizzled b128 reads ----
        const bf16x8 kh0A = *reinterpret_cast<const bf16x8*>(bK + kA0);
        const bf16x8 kh1A = *reinterpret_cast<const bf16x8*>(bK + kA1);
        const bf16x8 kh0B = *reinterpret_cast<const bf16x8*>(bK + 2048 + kA0);
        const bf16x8 kh1B = *reinterpret_cast<const bf16x8*>(bK + 2048 + kA1);
        const bf16x8 kl0A = *reinterpret_cast<const bf16x8*>(bK + 4096 + kA0);
        const bf16x8 kl1A = *reinterpret_cast<const bf16x8*>(bK + 4096 + kA1);
        const bf16x8 kl0B = *reinterpret_cast<const bf16x8*>(bK + 4096 + 2048 + kA0);
        const bf16x8 kl1B = *reinterpret_cast<const bf16x8*>(bK + 4096 + 2048 + kA1);

        // ---- QK^T: D[key][q], hi/lo split, base-2 logits ----
        f32x4 sA[2], sB[2];
        #pragma unroll
        for (int qs = 0; qs < 2; ++qs) {
            f32x4 s = zero4;
            s = mfma_bf16(kh0A, qh[qs][0], s);
            s = mfma_bf16(kh1A, qh[qs][1], s);
            s = mfma_bf16(kl0A, qh[qs][0], s);
            s = mfma_bf16(kl1A, qh[qs][1], s);
            s = mfma_bf16(kh0A, ql[qs][0], s);
            s = mfma_bf16(kh1A, ql[qs][1], s);
            sA[qs] = s;
            f32x4 u = zero4;
            u = mfma_bf16(kh0B, qh[qs][0], u);
            u = mfma_bf16(kh1B, qh[qs][1], u);
            u = mfma_bf16(kl0B, qh[qs][0], u);
            u = mfma_bf16(kl1B, qh[qs][1], u);
            u = mfma_bf16(kh0B, ql[qs][0], u);
            u = mfma_bf16(kh1B, ql[qs][1], u);
            sB[qs] = u;
        }

        // ---- defer-max (fast path: no cross-lane) ----
        float pm[2];
        #pragma unroll
        for (int qs = 0; qs < 2; ++qs)
            pm[qs] = fmaxf(fmaxf(fmaxf(sA[qs][0], sA[qs][1]), fmaxf(sA[qs][2], sA[qs][3])),
                           fmaxf(fmaxf(sB[qs][0], sB[qs][1]), fmaxf(sB[qs][2], sB[qs][3])));
        const float dmax = fmaxf(pm[0] - mr[0], pm[1] - mr[1]);
        if (__any(dmax > THR2)) {
            float m0 = pm[0], m1 = pm[1];
            m0 = fmaxf(m0, __shfl_xor(m0, 16, 64));
            m0 = fmaxf(m0, __shfl_xor(m0, 32, 64));
            m1 = fmaxf(m1, __shfl_xor(m1, 16, 64));
            m1 = fmaxf(m1, __shfl_xor(m1, 32, 64));
            const float n0 = fmaxf(mr[0], m0), n1 = fmaxf(mr[1], m1);
            const float a0 = fexp2(mr[0] - n0), a1 = fexp2(mr[1] - n1);
            mr[0] = n0; mr[1] = n1;
            rsum[0] *= a0; rsum[1] *= a1;
            #pragma unroll
            for (int r = 0; r < 4; ++r) {    // accO rows are q_local = lg*4+r
                const float b0 = __shfl(a0, lg * 4 + r, 64);
                const float b1 = __shfl(a1, lg * 4 + r, 64);
                #pragma unroll
                for (int c4 = 0; c4 < 4; ++c4) {
                    accO[0][c4][r] *= b0;
                    accO[1][c4][r] *= b1;
                }
            }
        }

        // ---- P = 2^(s-m); pack keys {lg*4+e} | {16+lg*4+e} into one bf16x8 ----
        bf16x8 pa8[2];
        #pragma unroll
        for (int qs = 0; qs < 2; ++qs) {
            float pA[4], pB[4];
            #pragma unroll
            for (int r = 0; r < 4; ++r) {
                pA[r] = fexp2(sA[qs][r] - mr[qs]);
                pB[r] = fexp2(sB[qs][r] - mr[qs]);
            }
            rsum[qs] += (pA[0] + pA[1] + pA[2] + pA[3]) + (pB[0] + pB[1] + pB[2] + pB[3]);
            uint4 pu;
            pu.x = pk2(pA[0], pA[1]); pu.y = pk2(pA[2], pA[3]);
            pu.z = pk2(pB[0], pB[1]); pu.w = pk2(pB[2], pB[3]);
            pa8[qs] = __builtin_bit_cast(bf16x8, pu);
        }

        // ---- PV: concat-K=32. B elem j<4 = V[key=lg*4+j][ch], j>=4 = V[16+lg*4+(j-4)][ch]
        //      (same key->kslot bijection as A side -> exact sum over keys) ----
        #pragma unroll
        for (int c4 = 0; c4 < 4; ++c4) {
            const int chb = (c4 * 16 + l16) * 64;
            const uint2 va = *reinterpret_cast<const uint2*>(bK + 8192 + chb + slotA);
            const uint2 vb = *reinterpret_cast<const uint2*>(bK + 8192 + chb + slotB);
            uint4 vu; vu.x = va.x; vu.y = va.y; vu.z = vb.x; vu.w = vb.y;
            const bf16x8 v8 = __builtin_bit_cast(bf16x8, vu);
            accO[0][c4] = mfma_bf16(pa8[0], v8, accO[0][c4]);
            accO[1][c4] = mfma_bf16(pa8[1], v8, accO[1][c4]);
        }

        __syncthreads();
        cur ^= 1;
    }

    // final l reduction over the 4 lane-groups sharing each q
    float rs[2] = { rsum[0], rsum[1] };
    #pragma unroll
    for (int qs = 0; qs < 2; ++qs) {
        rs[qs] += __shfl_xor(rs[qs], 16, 64);
        rs[qs] += __shfl_xor(rs[qs], 32, 64);
    }

    const size_t orow = (size_t)(seg * NB + b) * NN + q0 + w * 32;
    #pragma unroll
    for (int qs = 0; qs < 2; ++qs) {
        #pragma unroll
        for (int c4 = 0; c4 < 4; ++c4) {
            #pragma unroll
            for (int r = 0; r < 4; ++r) {
                Op[(orow + qs * 16 + lg * 4 + r) * NC + c4 * 16 + l16] =
                    __float2bfloat16(accO[qs][c4][r]);
            }
        }
    }
    if (lg == 0) {
        #pragma unroll
        for (int qs = 0; qs < 2; ++qs) {
            Mm[orow + qs * 16 + l16] = mr[qs];
            Ll[orow + qs * 16 + l16] = rs[qs];
        }
    }
}

// ---------------------------------------------------------------------------
// Kernel 3: merge KV-split partials + W conv + BN partial sums (LDS-reduced)
// ---------------------------------------------------------------------------
template<int NS>
__global__ __launch_bounds__(256) void k_wconv(
    const __hip_bfloat16* __restrict__ Op, const float* __restrict__ Mm,
    const float* __restrict__ Ll, const float* __restrict__ w_W,
    const float* __restrict__ b_W, float* __restrict__ Wy,
    float* __restrict__ stats)
{
    __shared__ float ys[NC][36];
    __shared__ float ws[NC][65];
    __shared__ float red[2][4][64];

    const int bid = blockIdx.x;
    const int b   = bid / (NN / 32);
    const int n0  = (bid % (NN / 32)) * 32;
    const int t   = threadIdx.x;
    const int o   = t & 63;
    const int pr  = (t >> 6) * 8;

    {   // merge NS segment partials for row n0+p, channels cb..cb+7
        const int p  = t >> 3;
        const int cb = (t & 7) * 8;
        const size_t row = (size_t)b * NN + n0 + p;
        float m[NS], lv[NS];
        #pragma unroll
        for (int s = 0; s < NS; ++s) {
            m[s]  = Mm[(size_t)s * NB * NN + row];
            lv[s] = Ll[(size_t)s * NB * NN + row];
        }
        float mstar = m[0];
        #pragma unroll
        for (int s = 1; s < NS; ++s) mstar = fmaxf(mstar, m[s]);
        float acc8[8];
        #pragma unroll
        for (int j = 0; j < 8; ++j) acc8[j] = 0.f;
        float L = 0.f;
        #pragma unroll
        for (int s = 0; s < NS; ++s) {
            const float wsc = fexp2(m[s] - mstar);
            L += wsc * lv[s];
            const bf16x8 a0 = *reinterpret_cast<const bf16x8*>(Op + ((size_t)s * NB * NN + row) * NC + cb);
            #pragma unroll
            for (int j = 0; j < 8; ++j) acc8[j] = fmaf(wsc, (float)a0[j], acc8[j]);
        }
        const float inv = 1.0f / L;
        #pragma unroll
        for (int j = 0; j < 8; ++j) ys[cb + j][p] = acc8[j] * inv;
    }
    {   // stage weights transposed
        const int oo = t & 63;
        const int cb = (t >> 6) * 16;
        const float4* src = reinterpret_cast<const float4*>(w_W + oo * NC + cb);
        float4 a0 = src[0], a1 = src[1], a2 = src[2], a3 = src[3];
        ws[cb +  0][oo] = a0.x; ws[cb +  1][oo] = a0.y; ws[cb +  2][oo] = a0.z; ws[cb +  3][oo] = a0.w;
        ws[cb +  4][oo] = a1.x; ws[cb +  5][oo] = a1.y; ws[cb +  6][oo] = a1.z; ws[cb +  7][oo] = a1.w;
        ws[cb +  8][oo] = a2.x; ws[cb +  9][oo] = a2.y; ws[cb + 10][oo] = a2.z; ws[cb + 11][oo] = a2.w;
        ws[cb + 12][oo] = a3.x; ws[cb + 13][oo] = a3.y; ws[cb + 14][oo] = a3.z; ws[cb + 15][oo] = a3.w;
    }
    __syncthreads();

    float acc[8];
    const float bb = b_W[o];
    #pragma unroll
    for (int i = 0; i < 8; ++i) acc[i] = bb;

    #pragma unroll 8
    for (int c = 0; c < NC; ++c) {
        const float wv = ws[c][o];
        const float4* xr = reinterpret_cast<const float4*>(&ys[c][pr]);
        #pragma unroll
        for (int q = 0; q < 2; ++q) {
            const float4 xv = xr[q];
            acc[4*q + 0] = fmaf(wv, xv.x, acc[4*q + 0]);
            acc[4*q + 1] = fmaf(wv, xv.y, acc[4*q + 1]);
            acc[4*q + 2] = fmaf(wv, xv.z, acc[4*q + 2]);
            acc[4*q + 3] = fmaf(wv, xv.w, acc[4*q + 3]);
        }
    }

    float s1 = 0.f, s2 = 0.f;
    #pragma unroll
    for (int i = 0; i < 8; ++i) { s1 += acc[i]; s2 += acc[i] * acc[i]; }

    float4* dst = reinterpret_cast<float4*>(Wy + (size_t)(b * NC + o) * NN + n0 + pr);
    const float4* av = reinterpret_cast<const float4*>(acc);
    dst[0] = av[0]; dst[1] = av[1];

    red[0][t >> 6][o] = s1;
    red[1][t >> 6][o] = s2;
    __syncthreads();
    if (t < 64) {
        const float r1 = red[0][0][t] + red[0][1][t] + red[0][2][t] + red[0][3][t];
        const float r2 = red[1][0][t] + red[1][1][t] + red[1][2][t] + red[1][3][t];
        atomicAdd(&stats[t], r1);
        atomicAdd(&stats[NC + t], r2);
    }
}

__global__ void k_zero(float* __restrict__ stats) {
    stats[threadIdx.x] = 0.f;
}

// ---------------------------------------------------------------------------
// Kernel 4: BN (training stats) + gamma/beta + residual
// ---------------------------------------------------------------------------
__global__ __launch_bounds__(256) void k_bn(
    const float* __restrict__ Wy, const float* __restrict__ x,
    const float* __restrict__ stats, const float* __restrict__ gamma,
    const float* __restrict__ beta, float* __restrict__ out)
{
    const int i = blockIdx.x * 256 + threadIdx.x;
    const int c = (i / (NN / 4)) % NC;
    const float n_inv = 1.0f / (float)(NB * NN);
    const float mean = stats[c] * n_inv;
    const float var  = stats[NC + c] * n_inv - mean * mean;
    const float rsq  = rsqrtf(var + BN_EPS);
    const float sc   = rsq * gamma[c];
    const float sh   = beta[c] - mean * sc;

    const float4 wv = reinterpret_cast<const float4*>(Wy)[i];
    const float4 xv = reinterpret_cast<const float4*>(x)[i];
    float4 ov;
    ov.x = wv.x * sc + sh + xv.x;
    ov.y = wv.y * sc + sh + xv.y;
    ov.z = wv.z * sc + sh + xv.z;
    ov.w = wv.w * sc + sh + xv.w;
    reinterpret_cast<float4*>(out)[i] = ov;
}

// ---------------------------------------------------------------------------
extern "C" void kernel_launch(void* const* d_in, const int* in_sizes, int n_in,
                              void* d_out, int out_size, void* d_ws, size_t ws_size,
                              hipStream_t stream)
{
    const float* x     = (const float*)d_in[0];
    const float* w_th  = (const float*)d_in[1];
    const float* b_th  = (const float*)d_in[2];
    const float* w_ph  = (const float*)d_in[3];
    const float* b_ph  = (const float*)d_in[4];
    const float* w_g   = (const float*)d_in[5];
    const float* b_g   = (const float*)d_in[6];
    const float* w_W   = (const float*)d_in[7];
    const float* b_W   = (const float*)d_in[8];
    const float* gamma = (const float*)d_in[9];
    const float* beta  = (const float*)d_in[10];
    float* out = (float*)d_out;

    const size_t nbh = (size_t)NB * NN * NC * sizeof(__hip_bfloat16);
    const size_t need8 = 5 * nbh + (size_t)8 * NB * NN * NC * 2 + (size_t)2 * 8 * NB * NN * 4 + 1024;
    const int ns = (ws_size >= need8) ? 8 : 4;

    char* p = (char*)d_ws;
    __hip_bfloat16* Qh = (__hip_bfloat16*)p; p += nbh;
    __hip_bfloat16* Ql = (__hip_bfloat16*)p; p += nbh;
    __hip_bfloat16* Kh = (__hip_bfloat16*)p; p += nbh;
    __hip_bfloat16* Kl = (__hip_bfloat16*)p; p += nbh;
    __hip_bfloat16* Vt = (__hip_bfloat16*)p; p += nbh;
    __hip_bfloat16* Op = (__hip_bfloat16*)p; p += (size_t)ns * NB * NN * NC * sizeof(__hip_bfloat16);
    float* Mm    = (float*)p; p += (size_t)ns * NB * NN * sizeof(float);
    float* Ll    = (float*)p; p += (size_t)ns * NB * NN * sizeof(float);
    float* stats = (float*)p;
    float* Wy = (float*)d_ws;   // aliases dead-by-then Qh/Ql region

    hipLaunchKernelGGL(k_zero, dim3(1), dim3(2 * NC), 0, stream, stats);
    hipLaunchKernelGGL(k_qkv, dim3(NB * NN / 32), dim3(256), 0, stream,
                       x, w_th, b_th, w_ph, b_ph, w_g, b_g, Qh, Ql, Kh, Kl, Vt);
    if (ns == 8) {
        hipLaunchKernelGGL(k_attn<8>, dim3(NB * 8 * (NN / QBLK)), dim3(256), 0, stream,
                           Qh, Ql, Kh, Kl, Vt, Op, Mm, Ll);
        hipLaunchKernelGGL(k_wconv<8>, dim3(NB * NN / 32), dim3(256), 0, stream,
                           Op, Mm, Ll, w_W, b_W, Wy, stats);
    } else {
        hipLaunchKernelGGL(k_attn<4>, dim3(NB * 4 * (NN / QBLK)), dim3(256), 0, stream,
                           Qh, Ql, Kh, Kl, Vt, Op, Mm, Ll);
        hipLaunchKernelGGL(k_wconv<4>, dim3(NB * NN / 32), dim3(256), 0, stream,
                           Op, Mm, Ll, w_W, b_W, Wy, stats);
    }
    hipLaunchKernelGGL(k_bn, dim3((NB * NC * NN / 4) / 256), dim3(256), 0, stream,
                       Wy, x, stats, gamma, beta, out);
}